// Round 1
// baseline (10800.311 us; speedup 1.0000x reference)
//
#include <hip/hip_runtime.h>
#include <cfloat>

// ---------------------------------------------------------------------------
// GCN3D forward, f32 end-to-end. Correctness-first baseline.
// B=8, N=2048 -> 512 -> 128, K_NB=50, S=1.
// Workspace use: ~98 MB (see offsets below).
// ---------------------------------------------------------------------------

#define BB   8
#define NP0  2048
#define NP1  512
#define NP2  128
#define KNB_ 50

// ---------------- workspace layout (byte offsets) ----------------
static constexpr size_t OFF_V0    = 0;          // 8*2048*3 f32
static constexpr size_t OFF_IDX0  = 196608;     // 8*2048*50 int
static constexpr size_t OFF_IDXP0 = 3473408;    // 8*512*4 int
static constexpr size_t OFF_IDX1  = 3538944;    // 8*512*50 int
static constexpr size_t OFF_IDXP1 = 4358144;    // 8*128*4 int
static constexpr size_t OFF_IDX2  = 4374528;    // 8*128*50 int
static constexpr size_t OFF_NI1   = 4579328;    // 8*2048 int
static constexpr size_t OFF_NI2   = 4644864;    // 8*2048 int
static constexpr size_t OFF_FGLOB = 4710400;    // 8*512 f32
static constexpr size_t OFF_GLOB1 = 4726784;    // 8*512 f32
static constexpr size_t OFF_COLS  = 4743168;    // 8*2048 f32
static constexpr size_t OFF_STATS = 4808704;    // 512*2 f32
static constexpr size_t OFF_FM0   = 4812800;    // 8*2048*128 f32
static constexpr size_t OFF_FM1   = 13201408;   // 8*2048*128
static constexpr size_t OFF_FM2   = 21590016;   // 8*512*256
static constexpr size_t OFF_FM3   = 25784320;   // 8*512*256
static constexpr size_t OFF_FM4   = 29978624;   // 8*128*512
static constexpr size_t OFF_FMP1  = 32075776;   // 8*512*128
static constexpr size_t OFF_FMP2  = 34172928;   // 8*128*256
static constexpr size_t OFF_Q     = 35221504;   // SA q (aliased by X1 later)
static constexpr size_t OFF_VMAT  = 37318656;   // SA v
static constexpr size_t OFF_XR    = 45707264;   // SA x_r
static constexpr size_t OFF_X1    = 35221504;   // 8*2048*512 (aliases Q/VMAT/XR; disjoint in time)
static constexpr size_t OFF_BIG   = 68775936;   // 32 MiB: attn groups / fout / pre / x2
// total = 102330368 bytes

// ===========================================================================
// kernels
// ===========================================================================

__global__ void k_transpose(const float* __restrict__ in, float* __restrict__ out) {
  int i = blockIdx.x * 256 + threadIdx.x;
  if (i >= BB * NP0 * 3) return;
  int d = i % 3;
  int t = (i / 3) % NP0;
  int b = i / (3 * NP0);
  out[i] = in[((size_t)b * 3 + d) * NP0 + t];
}

// wave-per-query KNN: selects K smallest (excluding self), tie -> smaller idx.
__global__ void k_knn(const float* __restrict__ pts, int ptsStride,
                      int Ncand, int Nq, int K, int* __restrict__ outIdx) {
  extern __shared__ float sm[];
  float* sp   = sm;               // Ncand*3 coords
  float* dist = sm + 3 * Ncand;   // 4 waves * Ncand
  int b = blockIdx.y;
  const float* pb = pts + (size_t)b * ptsStride;
  for (int i = threadIdx.x; i < Ncand * 3; i += 256) sp[i] = pb[i];
  __syncthreads();
  int wave = threadIdx.x >> 6, lane = threadIdx.x & 63;
  int qi = blockIdx.x * 4 + wave;
  float qx = sp[qi * 3], qy = sp[qi * 3 + 1], qz = sp[qi * 3 + 2];
  float* dw = dist + (size_t)wave * Ncand;
  for (int m = lane; m < Ncand; m += 64) {
    float dx = sp[m * 3] - qx, dy = sp[m * 3 + 1] - qy, dz = sp[m * 3 + 2] - qz;
    dw[m] = (m == qi) ? FLT_MAX : (dx * dx + dy * dy + dz * dz);
  }
  int* orow = outIdx + ((size_t)b * Nq + qi) * K;
  for (int s = 0; s < K; ++s) {
    float bd = FLT_MAX; int bi = 0x7fffffff;
    for (int m = lane; m < Ncand; m += 64) {
      float d = dw[m];
      if (d < bd) { bd = d; bi = m; }   // ascending scan keeps smallest idx on tie
    }
    for (int off = 32; off; off >>= 1) {
      float od = __shfl_xor(bd, off);
      int   oi = __shfl_xor(bi, off);
      if (od < bd || (od == bd && oi < bi)) { bd = od; bi = oi; }
    }
    // each dw[m] is owned (written & read) by lane m%64 only -> no barrier needed
    if ((bi & 63) == lane) dw[bi] = FLT_MAX;
    if (lane == 0) orow[s] = bi;
  }
}

// fm0[b,n,m] = max_k relu( unit(v[idx]-v[n]) . unitdir_m )
__global__ void k_conv_surface(const float* __restrict__ v, int vStride,
                               const int* __restrict__ idx,
                               const float* __restrict__ dirs,
                               float* __restrict__ out, int N, int M) {
  __shared__ float su[KNB_ * 3];
  int b = blockIdx.y, n = blockIdx.x, c = threadIdx.x;
  const float* vb = v + (size_t)b * vStride;
  float cx = vb[n * 3], cy = vb[n * 3 + 1], cz = vb[n * 3 + 2];
  const int* irow = idx + ((size_t)b * N + n) * KNB_;
  if (c < KNB_) {
    int j = irow[c];
    float dx = vb[j * 3] - cx, dy = vb[j * 3 + 1] - cy, dz = vb[j * 3 + 2] - cz;
    float inv = 1.f / fmaxf(sqrtf(dx * dx + dy * dy + dz * dz), 1e-12f);
    su[c * 3] = dx * inv; su[c * 3 + 1] = dy * inv; su[c * 3 + 2] = dz * inv;
  }
  __syncthreads();
  float d0 = dirs[c], d1 = dirs[M + c], d2 = dirs[2 * M + c];
  float inv = 1.f / fmaxf(sqrtf(d0 * d0 + d1 * d1 + d2 * d2), 1e-12f);
  d0 *= inv; d1 *= inv; d2 *= inv;
  float acc = 0.f;
  for (int k = 0; k < KNB_; ++k) {
    float t = fmaxf(su[k * 3] * d0 + su[k * 3 + 1] * d1 + su[k * 3 + 2] * d2, 0.f);
    acc = fmaxf(acc, t);
  }
  out[((size_t)b * N + n) * M + c] = acc;
}

// out[b,n,c] = fout[b,n,c] + max_k( relu(u_k . dir_c) * fout[b,idx_k,C+c] )
__global__ void k_conv_layer(const float* __restrict__ v, int vStride,
                             const int* __restrict__ idx,
                             const float* __restrict__ dirs,
                             const float* __restrict__ fout,
                             float* __restrict__ out, int N, int C) {
  __shared__ float su[KNB_ * 3];
  __shared__ int sidx[KNB_];
  int b = blockIdx.y, n = blockIdx.x, c = threadIdx.x;
  const float* vb = v + (size_t)b * vStride;
  float cx = vb[n * 3], cy = vb[n * 3 + 1], cz = vb[n * 3 + 2];
  const int* irow = idx + ((size_t)b * N + n) * KNB_;
  if (c < KNB_) {
    int j = irow[c]; sidx[c] = j;
    float dx = vb[j * 3] - cx, dy = vb[j * 3 + 1] - cy, dz = vb[j * 3 + 2] - cz;
    float inv = 1.f / fmaxf(sqrtf(dx * dx + dy * dy + dz * dz), 1e-12f);
    su[c * 3] = dx * inv; su[c * 3 + 1] = dy * inv; su[c * 3 + 2] = dz * inv;
  }
  __syncthreads();
  float d0 = dirs[c], d1 = dirs[C + c], d2 = dirs[2 * C + c];
  float inv = 1.f / fmaxf(sqrtf(d0 * d0 + d1 * d1 + d2 * d2), 1e-12f);
  d0 *= inv; d1 *= inv; d2 *= inv;
  const float* fb = fout + (size_t)b * N * 2 * C;
  float acc = -FLT_MAX;
  for (int k = 0; k < KNB_; ++k) {
    float t = fmaxf(su[k * 3] * d0 + su[k * 3 + 1] * d1 + su[k * 3 + 2] * d2, 0.f);
    float fs = fb[(size_t)sidx[k] * 2 * C + C + c];
    acc = fmaxf(acc, t * fs);
  }
  out[((size_t)b * N + n) * C + c] = fb[(size_t)n * 2 * C + c] + acc;
}

// generic tiled f32 GEMM: C[M,N] = (AREL?relu:id)(A[gidx?]) * B(^T) (+bias) (+=C)
template <bool AT, bool BT, bool BIAS, bool ACC, bool AREL>
__global__ __launch_bounds__(256) void k_gemm(
    const float* __restrict__ A, const float* __restrict__ Bm,
    const float* __restrict__ bias, float* __restrict__ Cm,
    int M, int N, int K, size_t sA, size_t sB, size_t sC,
    const int* __restrict__ gidx, size_t sG) {
  __shared__ float As[64][17];
  __shared__ float Bs[16][65];
  const int z = blockIdx.z;
  const float* Ab = A + (size_t)z * sA;
  const float* Bb = Bm + (size_t)z * sB;
  float* Cb = Cm + (size_t)z * sC;
  const int* gb = gidx ? (gidx + (size_t)z * sG) : nullptr;
  const int m0 = blockIdx.x * 64, n0 = blockIdx.y * 64;
  const int t = threadIdx.x;
  const int ty = t >> 4, tx = t & 15;
  float acc[4][4] = {{0.f}};
  for (int k0 = 0; k0 < K; k0 += 16) {
#pragma unroll
    for (int i = 0; i < 4; ++i) {
      int e = t + i * 256;
      int r, cc;
      if (AT) { r = e & 63; cc = e >> 6; }
      else    { r = e >> 4; cc = e & 15; }
      int gm = m0 + r, gk = k0 + cc;
      float val = 0.f;
      if (gm < M && gk < K) {
        if (AT) {
          val = Ab[(size_t)gk * M + gm];
        } else {
          int pr = gb ? gb[gm] : gm;
          val = Ab[(size_t)pr * K + gk];
        }
        if (AREL) val = fmaxf(val, 0.f);
      }
      As[r][cc] = val;
    }
#pragma unroll
    for (int i = 0; i < 4; ++i) {
      int e = t + i * 256;
      int r = e >> 6, cc = e & 63;
      int gk = k0 + r, gn = n0 + cc;
      float val = 0.f;
      if (gk < K && gn < N) val = BT ? Bb[(size_t)gn * K + gk] : Bb[(size_t)gk * N + gn];
      Bs[r][cc] = val;
    }
    __syncthreads();
#pragma unroll
    for (int kk = 0; kk < 16; ++kk) {
      float a[4], b4[4];
#pragma unroll
      for (int i = 0; i < 4; ++i) a[i] = As[ty * 4 + i][kk];
#pragma unroll
      for (int j = 0; j < 4; ++j) b4[j] = Bs[kk][tx * 4 + j];
#pragma unroll
      for (int i = 0; i < 4; ++i)
#pragma unroll
        for (int j = 0; j < 4; ++j) acc[i][j] = fmaf(a[i], b4[j], acc[i][j]);
    }
    __syncthreads();
  }
#pragma unroll
  for (int i = 0; i < 4; ++i) {
    int gm = m0 + ty * 4 + i;
    if (gm >= M) continue;
#pragma unroll
    for (int j = 0; j < 4; ++j) {
      int gn = n0 + tx * 4 + j;
      if (gn >= N) continue;
      float vv = acc[i][j];
      if (BIAS) vv += bias[gn];
      if (ACC) vv += Cb[(size_t)gm * N + gn];
      Cb[(size_t)gm * N + gn] = vv;
    }
  }
}

__global__ void k_bn_stats(const float* __restrict__ x, int rows, int C,
                           float* __restrict__ stats) {
  int c = blockIdx.x;
  float s = 0.f, s2 = 0.f;
  for (int r = threadIdx.x; r < rows; r += 256) {
    float v = x[(size_t)r * C + c];
    s += v; s2 += v * v;
  }
  __shared__ float ss[256], ss2[256];
  ss[threadIdx.x] = s; ss2[threadIdx.x] = s2;
  __syncthreads();
  for (int o = 128; o; o >>= 1) {
    if (threadIdx.x < o) { ss[threadIdx.x] += ss[threadIdx.x + o]; ss2[threadIdx.x] += ss2[threadIdx.x + o]; }
    __syncthreads();
  }
  if (threadIdx.x == 0) {
    float m = ss[0] / rows;
    float var = ss2[0] / rows - m * m;
    stats[c] = m;
    stats[C + c] = rsqrtf(var + 1e-5f);
  }
}

template <bool ADD>
__global__ void k_bn_apply(const float* __restrict__ x, const float* __restrict__ stats,
                           const float* __restrict__ g, const float* __restrict__ bb,
                           const float* __restrict__ base, float* __restrict__ out,
                           int total, int C) {
  int i = blockIdx.x * 256 + threadIdx.x;
  if (i >= total) return;
  int c = i % C;
  float v = (x[i] - stats[c]) * stats[C + c] * g[c] + bb[c];
  v = fmaxf(v, 0.f);
  out[i] = ADD ? base[i] + v : v;
}

__global__ void k_rowsoftmax(float* __restrict__ S, int N) {
  extern __shared__ float row[];
  __shared__ float red[256];
  int n = blockIdx.x;
  float* Sb = S + ((size_t)blockIdx.y * N + n) * N;
  float lmax = -FLT_MAX;
  for (int m = threadIdx.x; m < N; m += 256) { float v = Sb[m]; row[m] = v; lmax = fmaxf(lmax, v); }
  red[threadIdx.x] = lmax; __syncthreads();
  for (int o = 128; o; o >>= 1) {
    if (threadIdx.x < o) red[threadIdx.x] = fmaxf(red[threadIdx.x], red[threadIdx.x + o]);
    __syncthreads();
  }
  float mx = red[0]; __syncthreads();
  float lsum = 0.f;
  for (int m = threadIdx.x; m < N; m += 256) { float e = __expf(row[m] - mx); row[m] = e; lsum += e; }
  red[threadIdx.x] = lsum; __syncthreads();
  for (int o = 128; o; o >>= 1) {
    if (threadIdx.x < o) red[threadIdx.x] += red[threadIdx.x + o];
    __syncthreads();
  }
  float inv = 1.f / red[0];
  for (int m = threadIdx.x; m < N; m += 256) Sb[m] = row[m] * inv;
}

__global__ void k_colsum(const float* __restrict__ S, float* __restrict__ colsum, int N) {
  int m = blockIdx.x * 256 + threadIdx.x;
  if (m >= N) return;
  const float* Sb = S + (size_t)blockIdx.y * N * N;
  float s = 0.f;
  for (int n = 0; n < N; ++n) s += Sb[(size_t)n * N + m];
  colsum[(size_t)blockIdx.y * N + m] = s;
}

__global__ void k_xsub(const float* __restrict__ fm, const float* __restrict__ xr_raw,
                       const float* __restrict__ colsum, float* __restrict__ out,
                       int C, int total) {
  int i = blockIdx.x * 256 + threadIdx.x;
  if (i >= total) return;
  int row = i / C;
  out[i] = fm[i] - xr_raw[i] / (1e-9f + colsum[row]);
}

__global__ void k_pool(const float* __restrict__ fm, const int* __restrict__ idxp,
                       float* __restrict__ out, int Nin, int pn, int K, int C) {
  int b = blockIdx.y, p = blockIdx.x, c = threadIdx.x;
  const int* ir = idxp + ((size_t)b * pn + p) * K;
  const float* fb = fm + (size_t)b * Nin * C;
  float acc = -FLT_MAX;
  for (int k = 0; k < K; ++k) acc = fmaxf(acc, fb[(size_t)ir[k] * C + c]);
  out[((size_t)b * pn + p) * C + c] = acc;
}

__global__ void k_maxn(const float* __restrict__ fm, float* __restrict__ out, int N, int C) {
  int b = blockIdx.y;
  int c = blockIdx.x * 256 + threadIdx.x;
  if (c >= C) return;
  float acc = -FLT_MAX;
  for (int n = 0; n < N; ++n) acc = fmaxf(acc, fm[((size_t)b * N + n) * C + c]);
  out[(size_t)b * C + c] = acc;
}

__global__ void k_nearest(const float* __restrict__ vt, int vtStride,
                          const float* __restrict__ vs, int vsStride,
                          int Ns, int* __restrict__ out) {
  extern __shared__ float sp[];
  int b = blockIdx.y;
  const float* vsb = vs + (size_t)b * vsStride;
  for (int i = threadIdx.x; i < Ns * 3; i += 256) sp[i] = vsb[i];
  __syncthreads();
  int t = blockIdx.x * 256 + threadIdx.x;
  const float* vtb = vt + (size_t)b * vtStride;
  float tx = vtb[t * 3], ty = vtb[t * 3 + 1], tz = vtb[t * 3 + 2];
  float bd = FLT_MAX; int bi = 0;
  for (int s = 0; s < Ns; ++s) {
    float dx = sp[s * 3] - tx, dy = sp[s * 3 + 1] - ty, dz = sp[s * 3 + 2] - tz;
    float d = dx * dx + dy * dy + dz * dz;
    if (d < bd) { bd = d; bi = s; }
  }
  out[(size_t)b * NP0 + t] = bi;
}

// glob1[b,j] = h1_b[j] + fglob[b,:] @ h1_w[1280:1792, j] + onehot[b,:] @ h1_w[1792:1808, j]
__global__ void k_glob1(const float* __restrict__ fglob, const float* __restrict__ onehot,
                        const float* __restrict__ h1w, const float* __restrict__ h1b,
                        float* __restrict__ out) {
  int b = blockIdx.x, j = threadIdx.x;
  float s = h1b[j];
  for (int i = 0; i < 512; ++i) s = fmaf(fglob[b * 512 + i], h1w[(size_t)(1280 + i) * 512 + j], s);
  for (int i = 0; i < 16; ++i)  s = fmaf(onehot[b * 16 + i], h1w[(size_t)(1792 + i) * 512 + j], s);
  out[b * 512 + j] = s;
}

__global__ void k_fill_rows(const float* __restrict__ rowvec, float* __restrict__ out,
                            int N, int C) {
  int i = blockIdx.x * 256 + threadIdx.x;
  if (i >= BB * N * C) return;
  int c = i % C;
  int b = i / (N * C);
  out[i] = rowvec[b * C + c];
}

__global__ void k_logsoftmax(float* __restrict__ x, int rows, int C) {
  int r = blockIdx.x * 4 + (threadIdx.x >> 6);
  int lane = threadIdx.x & 63;
  if (r >= rows) return;
  float* xr = x + (size_t)r * C;
  float v = (lane < C) ? xr[lane] : -FLT_MAX;
  float mx = v;
  for (int o = 32; o; o >>= 1) mx = fmaxf(mx, __shfl_xor(mx, o));
  float e = (lane < C) ? __expf(v - mx) : 0.f;
  float s = e;
  for (int o = 32; o; o >>= 1) s += __shfl_xor(s, o);
  float lse = mx + logf(s);
  if (lane < C) xr[lane] = v - lse;
}

// ===========================================================================
// host helpers
// ===========================================================================

template <bool AT, bool BT, bool BIAS, bool ACC, bool AREL>
static void gemm_launch(hipStream_t st, const float* A, const float* Bm, const float* bias,
                        float* C, int M, int N, int K, size_t sA, size_t sB, size_t sC,
                        int Z, const int* gidx = nullptr, size_t sG = 0) {
  dim3 grid((M + 63) / 64, (N + 63) / 64, Z);
  k_gemm<AT, BT, BIAS, ACC, AREL><<<grid, 256, 0, st>>>(A, Bm, bias, C, M, N, K, sA, sB, sC, gidx, sG);
}

struct SaW { const float *qk, *vw, *vb, *tw, *tb, *g, *be; };

static void run_sa(hipStream_t st, float* x, int N, int C, int Q, SaW w,
                   float* qb, float* vm, float* xr, float* colsum, float* big, float* stats) {
  // q = x @ qk^T ; vmat = x @ vw^T + vb
  gemm_launch<false, true, false, false, false>(st, x, w.qk, nullptr, qb, N, Q, C,
                                                (size_t)N * C, 0, (size_t)N * Q, BB);
  gemm_launch<false, true, true, false, false>(st, x, w.vw, w.vb, vm, N, C, C,
                                               (size_t)N * C, 0, (size_t)N * C, BB);
  int bg = (int)(33554432ull / ((size_t)N * N * 4));
  if (bg > BB) bg = BB;
  for (int g0 = 0; g0 < BB; g0 += bg) {
    const float* qg = qb + (size_t)g0 * N * Q;
    // S = q @ q^T  (materialized attn group)
    gemm_launch<false, true, false, false, false>(st, qg, qg, nullptr, big, N, N, Q,
                                                  (size_t)N * Q, (size_t)N * Q, (size_t)N * N, bg);
    k_rowsoftmax<<<dim3(N, bg), 256, N * 4, st>>>(big, N);
    k_colsum<<<dim3((N + 255) / 256, bg), 256, 0, st>>>(big, colsum + (size_t)g0 * N, N);
    // xr_raw = attn^T @ vmat
    gemm_launch<true, false, false, false, false>(st, big, vm + (size_t)g0 * N * C, nullptr,
                                                  xr + (size_t)g0 * N * C, N, C, N,
                                                  (size_t)N * N, (size_t)N * C, (size_t)N * C, bg);
  }
  int total = BB * N * C;
  k_xsub<<<(total + 255) / 256, 256, 0, st>>>(x, xr, colsum, xr, C, total);
  // pre = (x - xr) @ tw^T + tb  (into big)
  gemm_launch<false, true, true, false, false>(st, xr, w.tw, w.tb, big, N, C, C,
                                               (size_t)N * C, 0, (size_t)N * C, BB);
  k_bn_stats<<<C, 256, 0, st>>>(big, BB * N, C, stats);
  k_bn_apply<true><<<(total + 255) / 256, 256, 0, st>>>(big, stats, w.g, w.be, x, x, total, C);
}

static void run_conv(hipStream_t st, const float* fmin, int Cin,
                     const float* w, const float* bias, const float* dirs,
                     const float* v, int vStride, const int* idx,
                     float* fout, float* outfm, int N, int C,
                     const float* bng, const float* bnb, float* stats, bool doBN) {
  gemm_launch<false, false, true, false, false>(st, fmin, w, bias, fout, N, 2 * C, Cin,
                                                (size_t)N * Cin, 0, (size_t)N * 2 * C, BB);
  k_conv_layer<<<dim3(N, BB), C, 0, st>>>(v, vStride, idx, dirs, fout, outfm, N, C);
  if (doBN) {
    int total = BB * N * C;
    k_bn_stats<<<C, 256, 0, st>>>(outfm, BB * N, C, stats);
    k_bn_apply<false><<<(total + 255) / 256, 256, 0, st>>>(outfm, stats, bng, bnb, nullptr, outfm, total, C);
  }
}

// ===========================================================================

extern "C" void kernel_launch(void* const* d_in, const int* in_sizes, int n_in,
                              void* d_out, int out_size, void* d_ws, size_t ws_size,
                              hipStream_t stream) {
  auto in = [&](int i) { return (const float*)d_in[i]; };
  char* ws = (char*)d_ws;

  float* v0    = (float*)(ws + OFF_V0);
  int*   idx0  = (int*)(ws + OFF_IDX0);
  int*   idxp0 = (int*)(ws + OFF_IDXP0);
  int*   idx1  = (int*)(ws + OFF_IDX1);
  int*   idxp1 = (int*)(ws + OFF_IDXP1);
  int*   idx2  = (int*)(ws + OFF_IDX2);
  int*   ni1   = (int*)(ws + OFF_NI1);
  int*   ni2   = (int*)(ws + OFF_NI2);
  float* fglob = (float*)(ws + OFF_FGLOB);
  float* glob1 = (float*)(ws + OFF_GLOB1);
  float* colsum= (float*)(ws + OFF_COLS);
  float* stats = (float*)(ws + OFF_STATS);
  float* fm0   = (float*)(ws + OFF_FM0);
  float* fm1   = (float*)(ws + OFF_FM1);
  float* fm2   = (float*)(ws + OFF_FM2);
  float* fm3   = (float*)(ws + OFF_FM3);
  float* fm4   = (float*)(ws + OFF_FM4);
  float* fmp1  = (float*)(ws + OFF_FMP1);
  float* fmp2  = (float*)(ws + OFF_FMP2);
  float* qbuf  = (float*)(ws + OFF_Q);
  float* vmat  = (float*)(ws + OFF_VMAT);
  float* xr    = (float*)(ws + OFF_XR);
  float* x1    = (float*)(ws + OFF_X1);
  float* big   = (float*)(ws + OFF_BIG);
  float* out   = (float*)d_out;

  const int VS0 = NP0 * 3;  // per-batch float stride of v0 (v1/v2 are row prefixes)

  // ---- geometry ----
  k_transpose<<<(BB * NP0 * 3 + 255) / 256, 256, 0, stream>>>(in(0), v0);
  k_knn<<<dim3(NP0 / 4, BB), 256, 7 * NP0 * 4, stream>>>(v0, VS0, NP0, NP0, KNB_, idx0);

  // ---- conv0 (surface) + bn0 ----
  k_conv_surface<<<dim3(NP0, BB), 128, 0, stream>>>(v0, VS0, idx0, in(2), fm0, NP0, 128);
  k_bn_stats<<<128, 256, 0, stream>>>(fm0, BB * NP0, 128, stats);
  k_bn_apply<false><<<(BB * NP0 * 128 + 255) / 256, 256, 0, stream>>>(
      fm0, stats, in(3), in(4), nullptr, fm0, BB * NP0 * 128, 128);

  // ---- sa0 ----
  run_sa(stream, fm0, NP0, 128, 32, {in(5), in(6), in(7), in(8), in(9), in(10), in(11)},
         qbuf, vmat, xr, colsum, big, stats);

  // ---- conv1 + bn1 + sa1 ----
  run_conv(stream, fm0, 128, in(12), in(13), in(14), v0, VS0, idx0, big, fm1, NP0, 128,
           in(15), in(16), stats, true);
  run_sa(stream, fm1, NP0, 128, 32, {in(17), in(18), in(19), in(20), in(21), in(22), in(23)},
         qbuf, vmat, xr, colsum, big, stats);

  // ---- pool1 (only first 512 queries needed) ----
  k_knn<<<dim3(NP1 / 4, BB), 256, 7 * NP0 * 4, stream>>>(v0, VS0, NP0, NP1, 4, idxp0);
  k_pool<<<dim3(NP1, BB), 128, 0, stream>>>(fm1, idxp0, fmp1, NP0, NP1, 4, 128);
  k_knn<<<dim3(NP1 / 4, BB), 256, 7 * NP1 * 4, stream>>>(v0, VS0, NP1, NP1, KNB_, idx1);

  // ---- conv2 + bn2 + sa2 ----
  run_conv(stream, fmp1, 128, in(24), in(25), in(26), v0, VS0, idx1, big, fm2, NP1, 256,
           in(27), in(28), stats, true);
  run_sa(stream, fm2, NP1, 256, 64, {in(29), in(30), in(31), in(32), in(33), in(34), in(35)},
         qbuf, vmat, xr, colsum, big, stats);

  // ---- conv3 + bn3 + sa3 ----
  run_conv(stream, fm2, 256, in(36), in(37), in(38), v0, VS0, idx1, big, fm3, NP1, 256,
           in(39), in(40), stats, true);
  run_sa(stream, fm3, NP1, 256, 64, {in(41), in(42), in(43), in(44), in(45), in(46), in(47)},
         qbuf, vmat, xr, colsum, big, stats);

  // ---- pool2 ----
  k_knn<<<dim3(NP2 / 4, BB), 256, 7 * NP1 * 4, stream>>>(v0, VS0, NP1, NP2, 4, idxp1);
  k_pool<<<dim3(NP2, BB), 256, 0, stream>>>(fm3, idxp1, fmp2, NP1, NP2, 4, 256);
  k_knn<<<dim3(NP2 / 4, BB), 256, 7 * NP2 * 4, stream>>>(v0, VS0, NP2, NP2, KNB_, idx2);

  // ---- conv4 (no bn) + sa4 ----
  run_conv(stream, fmp2, 256, in(48), in(49), in(50), v0, VS0, idx2, big, fm4, NP2, 512,
           nullptr, nullptr, stats, false);
  run_sa(stream, fm4, NP2, 512, 128, {in(51), in(52), in(53), in(54), in(55), in(56), in(57)},
         qbuf, vmat, xr, colsum, big, stats);

  // ---- global max + nearest-upsample indices ----
  k_maxn<<<dim3(2, BB), 256, 0, stream>>>(fm4, fglob, NP2, 512);
  k_nearest<<<dim3(NP0 / 256, BB), 256, NP1 * 3 * 4, stream>>>(v0, VS0, v0, VS0, NP1, ni1);
  k_nearest<<<dim3(NP0 / 256, BB), 256, NP2 * 3 * 4, stream>>>(v0, VS0, v0, VS0, NP2, ni2);

  // ---- head: x1 = fuse @ h1_w + h1_b  (segmented, fuse never materialized) ----
  const float* h1w = in(58);
  k_glob1<<<BB, 512, 0, stream>>>(fglob, in(1), h1w, in(59), glob1);
  k_fill_rows<<<(BB * NP0 * 512 + 255) / 256, 256, 0, stream>>>(glob1, x1, NP0, 512);
  gemm_launch<false, false, false, true, false>(stream, fm0, h1w + 0 * 512, nullptr, x1,
      NP0, 512, 128, (size_t)NP0 * 128, 0, (size_t)NP0 * 512, BB);
  gemm_launch<false, false, false, true, false>(stream, fm1, h1w + (size_t)128 * 512, nullptr, x1,
      NP0, 512, 128, (size_t)NP0 * 128, 0, (size_t)NP0 * 512, BB);
  gemm_launch<false, false, false, true, false>(stream, fm2, h1w + (size_t)256 * 512, nullptr, x1,
      NP0, 512, 256, (size_t)NP1 * 256, 0, (size_t)NP0 * 512, BB, ni1, (size_t)NP0);
  gemm_launch<false, false, false, true, false>(stream, fm3, h1w + (size_t)512 * 512, nullptr, x1,
      NP0, 512, 256, (size_t)NP1 * 256, 0, (size_t)NP0 * 512, BB, ni1, (size_t)NP0);
  gemm_launch<false, false, false, true, false>(stream, fm4, h1w + (size_t)768 * 512, nullptr, x1,
      NP0, 512, 512, (size_t)NP2 * 512, 0, (size_t)NP0 * 512, BB, ni2, (size_t)NP0);

  // x2 = relu(x1) @ h2_w + h2_b   (relu fused into A-read)
  gemm_launch<false, false, true, false, true>(stream, x1, in(60), in(61), big,
      NP0, 512, 512, (size_t)NP0 * 512, 0, (size_t)NP0 * 512, BB);
  // logits = relu(x2) @ h3_w + h3_b -> d_out
  gemm_launch<false, false, true, false, true>(stream, big, in(62), in(63), out,
      NP0, 50, 512, (size_t)NP0 * 512, 0, (size_t)NP0 * 50, BB);

  k_logsoftmax<<<(BB * NP0) / 4, 256, 0, stream>>>(out, BB * NP0, 50);
}

// Round 4
// 3294.800 us; speedup vs baseline: 3.2780x; 3.2780x over previous
//
#include <hip/hip_runtime.h>
#include <cfloat>

// ---------------------------------------------------------------------------
// GCN3D forward. Split-bf16 (Dekker) MFMA GEMMs: f32-grade accuracy on the
// matrix pipe. All activations/weights f32; only head x2 stored bf16.
// B=8, N=2048->512->128, K_NB=50, S=1. Workspace high-water 96,825,344 B.
// ---------------------------------------------------------------------------

#define BB   8
#define NP0  2048
#define NP1  512
#define NP2  128
#define KNB_ 50
#define VS0  (NP0 * 3)

typedef __attribute__((ext_vector_type(8))) short short8_t;
typedef __attribute__((ext_vector_type(4))) short short4_t;
typedef __attribute__((ext_vector_type(4))) float f32x4_t;

// ---------------- workspace layout (byte offsets) ----------------
static constexpr size_t O_V0    = 0;          //   196,608
static constexpr size_t O_IDX0  = 196608;     // 3,276,800
static constexpr size_t O_IDXP0 = 3473408;    //    65,536
static constexpr size_t O_IDX1  = 3538944;    //   819,200
static constexpr size_t O_IDXP1 = 4358144;    //    16,384
static constexpr size_t O_IDX2  = 4374528;    //   204,800
static constexpr size_t O_NI1   = 4579328;    //    65,536
static constexpr size_t O_NI2   = 4644864;    //    65,536
static constexpr size_t O_FGLOB = 4710400;    //    16,384
static constexpr size_t O_GLOB1 = 4726784;    //    16,384
static constexpr size_t O_COLS  = 4743168;    //    65,536
static constexpr size_t O_CPART = 4808704;    //   524,288
static constexpr size_t O_STATS = 5332992;    //     4,096
static constexpr size_t O_BPART = 5337088;    //   262,144
static constexpr size_t O_FM0   = 5599232;    // 8,388,608 (f32)
static constexpr size_t O_FM1   = 13987840;   // 8,388,608
static constexpr size_t O_FM2   = 22376448;   // 4,194,304
static constexpr size_t O_FM3   = 26570752;   // 4,194,304
static constexpr size_t O_FM4   = 30765056;   // 2,097,152
static constexpr size_t O_FMP1  = 32862208;   // 2,097,152
static constexpr size_t O_FMP2  = 34959360;   // 1,048,576
static constexpr size_t O_Q     = 36007936;   // 2,097,152
static constexpr size_t O_VM    = 38105088;   // 8,388,608
static constexpr size_t O_XS    = 46493696;   // 8,388,608
static constexpr size_t O_XR    = 54882304;   // 8,388,608
static constexpr size_t O_AREA  = 63270912;   // 33,554,432: S / fout / pre / x1
// AREA end = 96,825,344.
// Head aliases (phase-disjoint, verified):
//   x1 (f32, 33.5MB) = O_AREA            (S/fout dead at head)
//   x2b (bf16, 16.8MB) = O_FM0           (fm0/fm1 consumed by seg GEMMs)
static constexpr size_t O_X2B = O_FM0;

__device__ __forceinline__ float bf2f(unsigned short h) {
  union { unsigned u; float f; } c; c.u = ((unsigned)h) << 16; return c.f;
}
__device__ __forceinline__ unsigned short f2bf(float f) {
  union { float f; unsigned u; } c; c.f = f;
  return (unsigned short)((c.u + 0x7fffu + ((c.u >> 16) & 1u)) >> 16);
}
__device__ __forceinline__ short8_t pack8(short4_t lo, short4_t hi) {
  short8_t r;
  r[0]=lo[0]; r[1]=lo[1]; r[2]=lo[2]; r[3]=lo[3];
  r[4]=hi[0]; r[5]=hi[1]; r[6]=hi[2]; r[7]=hi[3];
  return r;
}

// ===========================================================================
// Split-bf16 MFMA GEMM. C[M,N] = A*B (+bias) (+=C), 64x64 tile, 4 waves.
// Each f32 operand staged as hi/lo bf16 planes; 3 MFMAs per fragment pair
// (ah*bh + ah*bl + al*bh), rel err ~1e-5.
// AMODE: 0 = A f32 [M,K] (optional row-gather GIDX, optional relu AREL)
//        1 = A f32 [K,M] (transposed source, e.g. attn^T)
//        2 = A bf16 [M,K] plain (lo=0; 2 MFMAs)
// BMODE: 0 = B f32 [K,N]   1 = B f32 [N,K] (i.e. B^T of weight [out,in])
// BIASM: 0 none, 1 bias[col] f32. OUTM: 0 f32, 2 relu->bf16. ACC: C += .
// ksplit: z = zb*ksplit+ks; each ks covers K/ksplit; C slab at z*sC.
// M multiple of 64; K multiple of 32*ksplit; N arbitrary (guarded).
// ===========================================================================
template <int AMODE, int BMODE, int BIASM, int OUTM, bool ACC, bool AREL, bool GIDX>
__global__ __launch_bounds__(256) void k_mm(
    const void* __restrict__ Av, const float* __restrict__ Bf0,
    const float* __restrict__ bias, void* __restrict__ Cv,
    int M, int N, int K, long sA, long sB, long sC, int ksplit,
    const int* __restrict__ gidx, long sG) {
  __shared__ unsigned short Ah[64][40], Bh[64][40], Bl[64][40];
  __shared__ unsigned short Al[(AMODE == 2) ? 1 : 64][40];
  const int z = blockIdx.z;
  const int zb = z / ksplit, ks = z - zb * ksplit;
  const int kchunk = K / ksplit;
  const int kl0 = ks * kchunk, kl1 = kl0 + kchunk;
  const int m0 = blockIdx.x * 64, n0 = blockIdx.y * 64;
  const int t = threadIdx.x;
  const int lane = t & 63, w = t >> 6;
  const int wr = (w >> 1) * 32, wc = (w & 1) * 32;
  const int frow = lane & 15, koff = (lane >> 4) * 8;
  f32x4_t acc[2][2];
#pragma unroll
  for (int i = 0; i < 2; ++i)
#pragma unroll
    for (int j = 0; j < 2; ++j) acc[i][j] = (f32x4_t){0.f, 0.f, 0.f, 0.f};

  const float* Af = (const float*)Av + (size_t)zb * sA;
  const unsigned short* Abf = (const unsigned short*)Av + (size_t)zb * sA;
  const float* Bf = Bf0 + (size_t)zb * sB;
  const int* gb = GIDX ? (gidx + (size_t)zb * sG) : nullptr;

  for (int k0 = kl0; k0 < kl1; k0 += 32) {
    __syncthreads();
    // ---- stage A ----
    if (AMODE == 0) {
      const int r = t >> 2, c = (t & 3) * 8;
      int row = m0 + r;
      if (GIDX) row = gb[row];
      const float* src = Af + (size_t)row * K + k0 + c;
#pragma unroll
      for (int j = 0; j < 8; ++j) {
        float v = src[j];
        if (AREL) v = fmaxf(v, 0.f);
        unsigned short h = f2bf(v);
        Ah[r][c + j] = h;
        Al[r][c + j] = f2bf(v - bf2f(h));
      }
    } else if (AMODE == 1) {
      const int m = t & 63, kq = (t >> 6) * 8;
      const float* src = Af + (size_t)(k0 + kq) * M + (m0 + m);
#pragma unroll
      for (int j = 0; j < 8; ++j) {
        float v = src[(size_t)j * M];
        unsigned short h = f2bf(v);
        Ah[m][kq + j] = h;
        Al[m][kq + j] = f2bf(v - bf2f(h));
      }
    } else {  // AMODE==2: plain bf16 [M,K]
      const int r = t >> 2, c = (t & 3) * 8;
      const short4_t* src = (const short4_t*)(Abf + (size_t)(m0 + r) * K + k0 + c);
      *(short4_t*)&Ah[r][c] = src[0];
      *(short4_t*)&Ah[r][c + 4] = src[1];
    }
    // ---- stage B ----
    if (BMODE == 0) {
      const int n = t & 63, kq = (t >> 6) * 8;
      const bool ok = (n0 + n) < N;
      const float* src = Bf + (size_t)(k0 + kq) * N + (n0 + n);
#pragma unroll
      for (int j = 0; j < 8; ++j) {
        float v = ok ? src[(size_t)j * N] : 0.f;
        unsigned short h = f2bf(v);
        Bh[n][kq + j] = h;
        Bl[n][kq + j] = f2bf(v - bf2f(h));
      }
    } else {
      const int n = t >> 2, c = (t & 3) * 8;
      const bool ok = (n0 + n) < N;
      const float* src = Bf + (size_t)(n0 + n) * K + k0 + c;
#pragma unroll
      for (int j = 0; j < 8; ++j) {
        float v = ok ? src[j] : 0.f;
        unsigned short h = f2bf(v);
        Bh[n][c + j] = h;
        Bl[n][c + j] = f2bf(v - bf2f(h));
      }
    }
    __syncthreads();
    short8_t ah[2], al[2], bh[2], bl[2];
#pragma unroll
    for (int rt = 0; rt < 2; ++rt) {
      const int r = wr + rt * 16 + frow;
      ah[rt] = pack8(*(const short4_t*)&Ah[r][koff], *(const short4_t*)&Ah[r][koff + 4]);
      if (AMODE != 2)
        al[rt] = pack8(*(const short4_t*)&Al[r][koff], *(const short4_t*)&Al[r][koff + 4]);
    }
#pragma unroll
    for (int ct = 0; ct < 2; ++ct) {
      const int r = wc + ct * 16 + frow;
      bh[ct] = pack8(*(const short4_t*)&Bh[r][koff], *(const short4_t*)&Bh[r][koff + 4]);
      bl[ct] = pack8(*(const short4_t*)&Bl[r][koff], *(const short4_t*)&Bl[r][koff + 4]);
    }
#pragma unroll
    for (int rt = 0; rt < 2; ++rt)
#pragma unroll
      for (int ct = 0; ct < 2; ++ct) {
        acc[rt][ct] = __builtin_amdgcn_mfma_f32_16x16x32_bf16(ah[rt], bh[ct], acc[rt][ct], 0, 0, 0);
        acc[rt][ct] = __builtin_amdgcn_mfma_f32_16x16x32_bf16(ah[rt], bl[ct], acc[rt][ct], 0, 0, 0);
        if (AMODE != 2)
          acc[rt][ct] = __builtin_amdgcn_mfma_f32_16x16x32_bf16(al[rt], bh[ct], acc[rt][ct], 0, 0, 0);
      }
  }

  const int crow = (lane >> 4) * 4;
#pragma unroll
  for (int rt = 0; rt < 2; ++rt) {
#pragma unroll
    for (int ct = 0; ct < 2; ++ct) {
      const int gc = n0 + wc + ct * 16 + frow;
      if (gc >= N) continue;
      const float bv = (BIASM == 1) ? bias[gc] : 0.f;
#pragma unroll
      for (int j = 0; j < 4; ++j) {
        const int gr = m0 + wr + rt * 16 + crow + j;
        float vv = acc[rt][ct][j] + bv;
        if (OUTM == 0) {
          float* Cp = (float*)Cv + (size_t)z * sC;
          if (ACC) vv += Cp[(size_t)gr * N + gc];
          Cp[(size_t)gr * N + gc] = vv;
        } else {
          vv = fmaxf(vv, 0.f);
          ((unsigned short*)Cv + (size_t)z * sC)[(size_t)gr * N + gc] = f2bf(vv);
        }
      }
    }
  }
}

template <int AMODE, int BMODE, int BIASM, int OUTM, bool ACC, bool AREL, bool GIDX>
static void mm(hipStream_t st, const void* A, const float* Bp, const float* bias,
               void* C, int M, int N, int K, long sA, long sB, long sC, int Z, int ksplit,
               const int* gidx = nullptr, long sG = 0) {
  dim3 grid(M / 64, (N + 63) / 64, Z * ksplit);
  k_mm<AMODE, BMODE, BIASM, OUTM, ACC, AREL, GIDX>
      <<<grid, 256, 0, st>>>(A, Bp, bias, C, M, N, K, sA, sB, sC, ksplit, gidx, sG);
}

// ===========================================================================
// KNN: register-resident distances, wave per query.
// ===========================================================================
template <int NCAND, int KSEL>
__global__ __launch_bounds__(256) void k_knn2(const float* __restrict__ pts, int Nq,
                                              int* __restrict__ outIdx) {
  __shared__ float sp[NCAND * 3];
  const int b = blockIdx.y;
  const float* pb = pts + (size_t)b * VS0;
  for (int i = threadIdx.x; i < NCAND * 3; i += 256) sp[i] = pb[i];
  __syncthreads();
  const int wave = threadIdx.x >> 6, lane = threadIdx.x & 63;
  const int qi = blockIdx.x * 4 + wave;
  const float qx = sp[qi * 3], qy = sp[qi * 3 + 1], qz = sp[qi * 3 + 2];
  constexpr int CH = NCAND / 64;
  float d[CH];
#pragma unroll
  for (int j = 0; j < CH; ++j) {
    const int m = lane + j * 64;
    const float dx = sp[m * 3] - qx, dy = sp[m * 3 + 1] - qy, dz = sp[m * 3 + 2] - qz;
    const float dd = dx * dx + dy * dy + dz * dz;
    d[j] = (m == qi) ? FLT_MAX : dd;
  }
  int* orow = outIdx + ((size_t)b * Nq + qi) * KSEL;
#pragma unroll 1
  for (int s = 0; s < KSEL; ++s) {
    float bd = FLT_MAX; int bj = 0;
#pragma unroll
    for (int j = 0; j < CH; ++j) {
      const bool better = d[j] < bd;
      bd = better ? d[j] : bd;
      bj = better ? j : bj;
    }
    int bm = lane + bj * 64;
#pragma unroll
    for (int off = 32; off; off >>= 1) {
      const float od = __shfl_xor(bd, off);
      const int om = __shfl_xor(bm, off);
      if (od < bd || (od == bd && om < bm)) { bd = od; bm = om; }
    }
    if (lane == 0) orow[s] = bm;
#pragma unroll
    for (int j = 0; j < CH; ++j)
      if (bm == lane + j * 64) d[j] = FLT_MAX;
  }
}

// ===========================================================================
// geometry / conv kernels (f32)
// ===========================================================================
__global__ void k_transpose(const float* __restrict__ in, float* __restrict__ out) {
  int i = blockIdx.x * 256 + threadIdx.x;
  if (i >= BB * NP0 * 3) return;
  int dd = i % 3, tt = (i / 3) % NP0, b = i / (3 * NP0);
  out[i] = in[((size_t)b * 3 + dd) * NP0 + tt];
}

__global__ void k_conv_surface(const float* __restrict__ v, const int* __restrict__ idx,
                               const float* __restrict__ dirs, float* __restrict__ out,
                               int N, int M) {
  __shared__ float su[KNB_ * 3];
  int b = blockIdx.y, n = blockIdx.x, c = threadIdx.x;
  const float* vb = v + (size_t)b * VS0;
  float cx = vb[n * 3], cy = vb[n * 3 + 1], cz = vb[n * 3 + 2];
  const int* irow = idx + ((size_t)b * N + n) * KNB_;
  if (c < KNB_) {
    int j = irow[c];
    float dx = vb[j * 3] - cx, dy = vb[j * 3 + 1] - cy, dz = vb[j * 3 + 2] - cz;
    float inv = 1.f / fmaxf(sqrtf(dx * dx + dy * dy + dz * dz), 1e-12f);
    su[c * 3] = dx * inv; su[c * 3 + 1] = dy * inv; su[c * 3 + 2] = dz * inv;
  }
  __syncthreads();
  float d0 = dirs[c], d1 = dirs[M + c], d2 = dirs[2 * M + c];
  float inv = 1.f / fmaxf(sqrtf(d0 * d0 + d1 * d1 + d2 * d2), 1e-12f);
  d0 *= inv; d1 *= inv; d2 *= inv;
  float acc = 0.f;
  for (int k = 0; k < KNB_; ++k) {
    float th = fmaxf(su[k * 3] * d0 + su[k * 3 + 1] * d1 + su[k * 3 + 2] * d2, 0.f);
    acc = fmaxf(acc, th);
  }
  out[((size_t)b * N + n) * M + c] = acc;
}

__global__ void k_conv_layer(const float* __restrict__ v, const int* __restrict__ idx,
                             const float* __restrict__ dirs, const float* __restrict__ fout,
                             float* __restrict__ out, int N, int C) {
  __shared__ float su[KNB_ * 3];
  __shared__ int sidx[KNB_];
  int b = blockIdx.y, n = blockIdx.x, c = threadIdx.x;
  const float* vb = v + (size_t)b * VS0;
  float cx = vb[n * 3], cy = vb[n * 3 + 1], cz = vb[n * 3 + 2];
  const int* irow = idx + ((size_t)b * N + n) * KNB_;
  if (c < KNB_) {
    int j = irow[c]; sidx[c] = j;
    float dx = vb[j * 3] - cx, dy = vb[j * 3 + 1] - cy, dz = vb[j * 3 + 2] - cz;
    float inv = 1.f / fmaxf(sqrtf(dx * dx + dy * dy + dz * dz), 1e-12f);
    su[c * 3] = dx * inv; su[c * 3 + 1] = dy * inv; su[c * 3 + 2] = dz * inv;
  }
  __syncthreads();
  float d0 = dirs[c], d1 = dirs[C + c], d2 = dirs[2 * C + c];
  float inv = 1.f / fmaxf(sqrtf(d0 * d0 + d1 * d1 + d2 * d2), 1e-12f);
  d0 *= inv; d1 *= inv; d2 *= inv;
  const float* fb = fout + (size_t)b * N * 2 * C;
  float acc = -FLT_MAX;
  for (int k = 0; k < KNB_; ++k) {
    float th = fmaxf(su[k * 3] * d0 + su[k * 3 + 1] * d1 + su[k * 3 + 2] * d2, 0.f);
    float fs = fb[(size_t)sidx[k] * 2 * C + C + c];
    acc = fmaxf(acc, th * fs);
  }
  out[((size_t)b * N + n) * C + c] = fb[(size_t)n * 2 * C + c] + acc;
}

// ===========================================================================
// BN (2-phase), softmax, colsum (2-phase), misc
// ===========================================================================
__global__ void k_bn_part(const float* __restrict__ x, int rows, int C, float* __restrict__ part) {
  const int blk = blockIdx.x;
  const int chunk = rows / 64;
  const int r0 = blk * chunk;
  const int c0 = threadIdx.x, c1 = threadIdx.x + 256;
  float s0 = 0, s20 = 0, s1 = 0, s21 = 0;
  for (int r = 0; r < chunk; ++r) {
    const float* row = x + (size_t)(r0 + r) * C;
    if (c0 < C) { float v = row[c0]; s0 += v; s20 += v * v; }
    if (c1 < C) { float v = row[c1]; s1 += v; s21 += v * v; }
  }
  float* p = part + (size_t)blk * 1024;
  if (c0 < C) { p[c0] = s0; p[512 + c0] = s20; }
  if (c1 < C) { p[c1] = s1; p[512 + c1] = s21; }
}

__global__ void k_bn_fin(const float* __restrict__ part, int rows, int C, float* __restrict__ stats) {
  int c = blockIdx.x * 256 + threadIdx.x;
  if (c >= C) return;
  float s = 0, s2 = 0;
  for (int b2 = 0; b2 < 64; ++b2) { s += part[b2 * 1024 + c]; s2 += part[b2 * 1024 + 512 + c]; }
  float m = s / rows;
  float var = s2 / rows - m * m;
  stats[c] = m;
  stats[C + c] = rsqrtf(var + 1e-5f);
}

template <bool ADD>
__global__ void k_bn_apply(const float* __restrict__ x, const float* __restrict__ stats,
                           const float* __restrict__ g, const float* __restrict__ bb,
                           const float* __restrict__ base, float* __restrict__ out,
                           int total, int C) {
  int i = blockIdx.x * 256 + threadIdx.x;
  if (i >= total) return;
  int c = i % C;
  float v = (x[i] - stats[c]) * stats[C + c] * g[c] + bb[c];
  v = fmaxf(v, 0.f);
  out[i] = ADD ? base[i] + v : v;
}

__global__ void k_rowsoftmax(float* __restrict__ S, int N) {
  extern __shared__ float row[];
  __shared__ float red[256];
  int n = blockIdx.x;
  float* Sb = S + ((size_t)blockIdx.y * N + n) * N;
  float lmax = -FLT_MAX;
  for (int m = threadIdx.x; m < N; m += 256) { float v = Sb[m]; row[m] = v; lmax = fmaxf(lmax, v); }
  red[threadIdx.x] = lmax; __syncthreads();
  for (int o = 128; o; o >>= 1) {
    if (threadIdx.x < o) red[threadIdx.x] = fmaxf(red[threadIdx.x], red[threadIdx.x + o]);
    __syncthreads();
  }
  float mx = red[0]; __syncthreads();
  float lsum = 0.f;
  for (int m = threadIdx.x; m < N; m += 256) { float e = __expf(row[m] - mx); row[m] = e; lsum += e; }
  red[threadIdx.x] = lsum; __syncthreads();
  for (int o = 128; o; o >>= 1) {
    if (threadIdx.x < o) red[threadIdx.x] += red[threadIdx.x + o];
    __syncthreads();
  }
  float inv = 1.f / red[0];
  for (int m = threadIdx.x; m < N; m += 256) Sb[m] = row[m] * inv;
}

__global__ void k_cs_part(const float* __restrict__ S, int N, float* __restrict__ cpart, int gbase) {
  int m = blockIdx.x * 256 + threadIdx.x;
  if (m >= N) return;
  int g = blockIdx.y, pc = blockIdx.z;
  int chunk = N / 8;
  const float* Sb = S + (size_t)g * N * N;
  float s = 0;
  for (int n = pc * chunk; n < (pc + 1) * chunk; ++n) s += Sb[(size_t)n * N + m];
  cpart[((size_t)pc * 8 + (gbase + g)) * 2048 + m] = s;
}

__global__ void k_cs_fin(const float* __restrict__ cpart, int N, float* __restrict__ colsum, int gbase) {
  int m = blockIdx.x * 256 + threadIdx.x;
  if (m >= N) return;
  int b = gbase + blockIdx.y;
  float s = 0;
#pragma unroll
  for (int pc = 0; pc < 8; ++pc) s += cpart[((size_t)pc * 8 + b) * 2048 + m];
  colsum[(size_t)b * N + m] = s;
}

__global__ void k_xsub_sk(const float* __restrict__ xrpart, const float* __restrict__ colsum,
                          const float* __restrict__ fm, float* __restrict__ xs,
                          int Npts, int C, int KS, int gbase, int gg) {
  int i = blockIdx.x * 256 + threadIdx.x;
  int per = Npts * C;
  if (i >= gg * per) return;
  int zb = i / per, rem = i - zb * per;
  int n = rem / C;
  float s = 0;
  for (int k2 = 0; k2 < KS; ++k2) s += xrpart[(size_t)(zb * KS + k2) * per + rem];
  int b = gbase + zb;
  xs[(size_t)b * per + rem] = fm[(size_t)b * per + rem] - s / (1e-9f + colsum[(size_t)b * Npts + n]);
}

__global__ void k_pool(const float* __restrict__ fm, const int* __restrict__ idxp,
                       float* __restrict__ out, int Nin, int pn, int C) {
  int b = blockIdx.y, p = blockIdx.x, c = threadIdx.x;
  const int* ir = idxp + ((size_t)b * pn + p) * 4;
  const float* fb = fm + (size_t)b * Nin * C;
  float acc = -FLT_MAX;
#pragma unroll
  for (int k = 0; k < 4; ++k) acc = fmaxf(acc, fb[(size_t)ir[k] * C + c]);
  out[((size_t)b * pn + p) * C + c] = acc;
}

__global__ void k_maxn(const float* __restrict__ fm, float* __restrict__ out, int N, int C) {
  int b = blockIdx.y;
  int c = blockIdx.x * 256 + threadIdx.x;
  if (c >= C) return;
  float acc = -FLT_MAX;
  for (int n = 0; n < N; ++n) acc = fmaxf(acc, fm[((size_t)b * N + n) * C + c]);
  out[(size_t)b * C + c] = acc;
}

__global__ void k_nearest(const float* __restrict__ v, int Ns, int* __restrict__ out) {
  extern __shared__ float sp[];
  int b = blockIdx.y;
  const float* vsb = v + (size_t)b * VS0;
  for (int i = threadIdx.x; i < Ns * 3; i += 256) sp[i] = vsb[i];
  __syncthreads();
  int t = blockIdx.x * 256 + threadIdx.x;
  float tx = vsb[t * 3], ty = vsb[t * 3 + 1], tz = vsb[t * 3 + 2];
  float bd = FLT_MAX; int bi = 0;
#pragma unroll 4
  for (int s = 0; s < Ns; ++s) {
    float dx = sp[s * 3] - tx, dy = sp[s * 3 + 1] - ty, dz = sp[s * 3 + 2] - tz;
    float dd = dx * dx + dy * dy + dz * dz;
    if (dd < bd) { bd = dd; bi = s; }
  }
  out[(size_t)b * NP0 + t] = bi;
}

__global__ void k_glob1(const float* __restrict__ fglob, const float* __restrict__ onehot,
                        const float* __restrict__ h1w, const float* __restrict__ h1b,
                        float* __restrict__ out) {
  int b = blockIdx.x, j = threadIdx.x;
  float s = h1b[j];
  for (int i = 0; i < 512; ++i) s = fmaf(fglob[b * 512 + i], h1w[(size_t)(1280 + i) * 512 + j], s);
  for (int i = 0; i < 16; ++i) s = fmaf(onehot[b * 16 + i], h1w[(size_t)(1792 + i) * 512 + j], s);
  out[b * 512 + j] = s;
}

__global__ void k_fill_rows(const float* __restrict__ rowvec, float* __restrict__ out,
                            int N, int C) {
  int i = blockIdx.x * 256 + threadIdx.x;
  if (i >= BB * N * C) return;
  int c = i % C;
  int b = i / (N * C);
  out[i] = rowvec[b * C + c];
}

__global__ void k_logsoftmax(float* __restrict__ x, int rows, int C) {
  int r = blockIdx.x * 4 + (threadIdx.x >> 6);
  int lane = threadIdx.x & 63;
  if (r >= rows) return;
  float* xr = x + (size_t)r * C;
  float v = (lane < C) ? xr[lane] : -FLT_MAX;
  float mx = v;
  for (int o = 32; o; o >>= 1) mx = fmaxf(mx, __shfl_xor(mx, o));
  float e = (lane < C) ? __expf(v - mx) : 0.f;
  float s = e;
  for (int o = 32; o; o >>= 1) s += __shfl_xor(s, o);
  float lse = mx + logf(s);
  if (lane < C) xr[lane] = v - lse;
}

// ===========================================================================
// host helpers
// ===========================================================================
struct Ws {
  float *v0, *fglob, *glob1, *colsum, *cpart, *stats, *bpart;
  float *fm0, *fm1, *fm2, *fm3, *fm4, *fmp1, *fmp2;
  float *q, *vm, *xs, *xr, *S, *pre, *fout, *x1;
  unsigned short* x2b;
  int *idx0, *idxp0, *idx1, *idxp1, *idx2, *ni1, *ni2;
};

struct SaW { const float *qk, *vw, *vb, *tw, *tb, *g, *be; };

static void run_sa(hipStream_t st, float* x, int N, int C, int Q, SaW w, Ws& ws) {
  // q = x @ qk^T ; vmat = x @ vw^T + vb
  mm<0, 1, 0, 0, false, false, false>(st, x, w.qk, nullptr, ws.q, N, Q, C,
                                      (long)N * C, 0, (long)N * Q, BB, 1);
  mm<0, 1, 1, 0, false, false, false>(st, x, w.vw, w.vb, ws.vm, N, C, C,
                                      (long)N * C, 0, (long)N * C, BB, 1);
  const int bg = (N == NP0) ? 2 : BB;
  const int KS = (N == NP0) ? 4 : (N == NP2 ? 2 : 1);
  const int per = N * C;
  for (int g0 = 0; g0 < BB; g0 += bg) {
    const float* qg = ws.q + (size_t)g0 * N * Q;
    mm<0, 1, 0, 0, false, false, false>(st, qg, qg, nullptr, ws.S, N, N, Q,
                                        (long)N * Q, (long)N * Q, (long)N * N, bg, 1);
    k_rowsoftmax<<<dim3(N, bg), 256, N * 4, st>>>(ws.S, N);
    k_cs_part<<<dim3((N + 255) / 256, bg, 8), 256, 0, st>>>(ws.S, N, ws.cpart, g0);
    k_cs_fin<<<dim3((N + 255) / 256, bg), 256, 0, st>>>(ws.cpart, N, ws.colsum, g0);
    // xr = attn^T @ vmat  (A = S f32 [K=N, M=N] transposed-source, ksplit)
    mm<1, 0, 0, 0, false, false, false>(st, ws.S, ws.vm + (size_t)g0 * N * C, nullptr, ws.xr,
                                        N, C, N, (long)N * N, (long)N * C, (long)N * C, bg, KS);
    k_xsub_sk<<<(bg * per + 255) / 256, 256, 0, st>>>(ws.xr, ws.colsum, x, ws.xs,
                                                      N, C, KS, g0, bg);
  }
  // pre = xs @ tw^T + tb
  mm<0, 1, 1, 0, false, false, false>(st, ws.xs, w.tw, w.tb, ws.pre, N, C, C,
                                      (long)N * C, 0, (long)N * C, BB, 1);
  k_bn_part<<<64, 256, 0, st>>>(ws.pre, BB * N, C, ws.bpart);
  k_bn_fin<<<(C + 255) / 256, 256, 0, st>>>(ws.bpart, BB * N, C, ws.stats);
  k_bn_apply<true><<<(BB * per + 255) / 256, 256, 0, st>>>(ws.pre, ws.stats, w.g, w.be,
                                                           x, x, BB * per, C);
}

static void run_conv(hipStream_t st, const float* fmin, int Cin,
                     const float* w, const float* bias, const float* dirs,
                     const int* idx, float* fm, int N, int C,
                     const float* bng, const float* bnb, bool doBN, Ws& ws) {
  mm<0, 0, 1, 0, false, false, false>(st, fmin, w, bias, ws.fout, N, 2 * C, Cin,
                                      (long)N * Cin, 0, (long)N * 2 * C, BB, 1);
  k_conv_layer<<<dim3(N, BB), C, 0, st>>>(ws.v0, idx, dirs, ws.fout, fm, N, C);
  if (doBN) {
    k_bn_part<<<64, 256, 0, st>>>(fm, BB * N, C, ws.bpart);
    k_bn_fin<<<(C + 255) / 256, 256, 0, st>>>(ws.bpart, BB * N, C, ws.stats);
    k_bn_apply<false><<<(BB * N * C + 255) / 256, 256, 0, st>>>(fm, ws.stats, bng, bnb,
                                                                nullptr, fm, BB * N * C, C);
  }
}

// ===========================================================================
extern "C" void kernel_launch(void* const* d_in, const int* in_sizes, int n_in,
                              void* d_out, int out_size, void* d_ws, size_t ws_size,
                              hipStream_t stream) {
  auto in = [&](int i) { return (const float*)d_in[i]; };
  char* p = (char*)d_ws;
  Ws ws;
  ws.v0 = (float*)(p + O_V0);
  ws.idx0 = (int*)(p + O_IDX0); ws.idxp0 = (int*)(p + O_IDXP0);
  ws.idx1 = (int*)(p + O_IDX1); ws.idxp1 = (int*)(p + O_IDXP1);
  ws.idx2 = (int*)(p + O_IDX2);
  ws.ni1 = (int*)(p + O_NI1); ws.ni2 = (int*)(p + O_NI2);
  ws.fglob = (float*)(p + O_FGLOB); ws.glob1 = (float*)(p + O_GLOB1);
  ws.colsum = (float*)(p + O_COLS); ws.cpart = (float*)(p + O_CPART);
  ws.stats = (float*)(p + O_STATS); ws.bpart = (float*)(p + O_BPART);
  ws.fm0 = (float*)(p + O_FM0); ws.fm1 = (float*)(p + O_FM1);
  ws.fm2 = (float*)(p + O_FM2); ws.fm3 = (float*)(p + O_FM3);
  ws.fm4 = (float*)(p + O_FM4);
  ws.fmp1 = (float*)(p + O_FMP1); ws.fmp2 = (float*)(p + O_FMP2);
  ws.q = (float*)(p + O_Q); ws.vm = (float*)(p + O_VM);
  ws.xs = (float*)(p + O_XS); ws.xr = (float*)(p + O_XR);
  ws.S = (float*)(p + O_AREA); ws.pre = (float*)(p + O_AREA);
  ws.fout = (float*)(p + O_AREA);
  ws.x1 = (float*)(p + O_AREA);
  ws.x2b = (unsigned short*)(p + O_X2B);
  float* out = (float*)d_out;

  // ---- geometry ----
  k_transpose<<<(BB * NP0 * 3 + 255) / 256, 256, 0, stream>>>(in(0), ws.v0);
  k_knn2<NP0, KNB_><<<dim3(NP0 / 4, BB), 256, 0, stream>>>(ws.v0, NP0, ws.idx0);

  // ---- conv0 + bn0 (into fm0) ----
  k_conv_surface<<<dim3(NP0, BB), 128, 0, stream>>>(ws.v0, ws.idx0, in(2), ws.fm0, NP0, 128);
  k_bn_part<<<64, 256, 0, stream>>>(ws.fm0, BB * NP0, 128, ws.bpart);
  k_bn_fin<<<1, 256, 0, stream>>>(ws.bpart, BB * NP0, 128, ws.stats);
  k_bn_apply<false><<<(BB * NP0 * 128 + 255) / 256, 256, 0, stream>>>(
      ws.fm0, ws.stats, in(3), in(4), nullptr, ws.fm0, BB * NP0 * 128, 128);

  // ---- sa0, conv1+bn1, sa1 ----
  run_sa(stream, ws.fm0, NP0, 128, 32, {in(5), in(6), in(7), in(8), in(9), in(10), in(11)}, ws);
  run_conv(stream, ws.fm0, 128, in(12), in(13), in(14), ws.idx0, ws.fm1,
           NP0, 128, in(15), in(16), true, ws);
  run_sa(stream, ws.fm1, NP0, 128, 32, {in(17), in(18), in(19), in(20), in(21), in(22), in(23)}, ws);

  // ---- pool1, knn1 ----
  k_knn2<NP0, 4><<<dim3(NP1 / 4, BB), 256, 0, stream>>>(ws.v0, NP1, ws.idxp0);
  k_pool<<<dim3(NP1, BB), 128, 0, stream>>>(ws.fm1, ws.idxp0, ws.fmp1, NP0, NP1, 128);
  k_knn2<NP1, KNB_><<<dim3(NP1 / 4, BB), 256, 0, stream>>>(ws.v0, NP1, ws.idx1);

  // ---- conv2+bn2, sa2, conv3+bn3, sa3 ----
  run_conv(stream, ws.fmp1, 128, in(24), in(25), in(26), ws.idx1, ws.fm2,
           NP1, 256, in(27), in(28), true, ws);
  run_sa(stream, ws.fm2, NP1, 256, 64, {in(29), in(30), in(31), in(32), in(33), in(34), in(35)}, ws);
  run_conv(stream, ws.fm2, 256, in(36), in(37), in(38), ws.idx1, ws.fm3,
           NP1, 256, in(39), in(40), true, ws);
  run_sa(stream, ws.fm3, NP1, 256, 64, {in(41), in(42), in(43), in(44), in(45), in(46), in(47)}, ws);

  // ---- pool2, knn2, conv4 (no bn), sa4 ----
  k_knn2<NP1, 4><<<dim3(NP2 / 4, BB), 256, 0, stream>>>(ws.v0, NP2, ws.idxp1);
  k_pool<<<dim3(NP2, BB), 256, 0, stream>>>(ws.fm3, ws.idxp1, ws.fmp2, NP1, NP2, 256);
  k_knn2<NP2, KNB_><<<dim3(NP2 / 4, BB), 256, 0, stream>>>(ws.v0, NP2, ws.idx2);
  run_conv(stream, ws.fmp2, 256, in(48), in(49), in(50), ws.idx2, ws.fm4,
           NP2, 512, nullptr, nullptr, false, ws);
  run_sa(stream, ws.fm4, NP2, 512, 128, {in(51), in(52), in(53), in(54), in(55), in(56), in(57)}, ws);

  // ---- global max, nearest, head ----
  k_maxn<<<dim3(2, BB), 256, 0, stream>>>(ws.fm4, ws.fglob, NP2, 512);
  k_nearest<<<dim3(NP0 / 256, BB), 256, NP1 * 3 * 4, stream>>>(ws.v0, NP1, ws.ni1);
  k_nearest<<<dim3(NP0 / 256, BB), 256, NP2 * 3 * 4, stream>>>(ws.v0, NP2, ws.ni2);
  const float* h1w = in(58);
  k_glob1<<<BB, 512, 0, stream>>>(ws.fglob, in(1), h1w, in(59), ws.glob1);

  // x1 = glob-init + 5 accumulating feature-segment GEMMs (exact f32 adds)
  k_fill_rows<<<(BB * NP0 * 512 + 255) / 256, 256, 0, stream>>>(ws.glob1, ws.x1, NP0, 512);
  mm<0, 0, 0, 0, true, false, false>(stream, ws.fm0, h1w, nullptr, ws.x1,
      NP0, 512, 128, (long)NP0 * 128, 0, (long)NP0 * 512, BB, 1);
  mm<0, 0, 0, 0, true, false, false>(stream, ws.fm1, h1w + (size_t)128 * 512, nullptr, ws.x1,
      NP0, 512, 128, (long)NP0 * 128, 0, (long)NP0 * 512, BB, 1);
  mm<0, 0, 0, 0, true, false, true>(stream, ws.fm2, h1w + (size_t)256 * 512, nullptr, ws.x1,
      NP0, 512, 256, (long)NP1 * 256, 0, (long)NP0 * 512, BB, 1, ws.ni1, NP0);
  mm<0, 0, 0, 0, true, false, true>(stream, ws.fm3, h1w + (size_t)512 * 512, nullptr, ws.x1,
      NP0, 512, 256, (long)NP1 * 256, 0, (long)NP0 * 512, BB, 1, ws.ni1, NP0);
  mm<0, 0, 0, 0, true, false, true>(stream, ws.fm4, h1w + (size_t)768 * 512, nullptr, ws.x1,
      NP0, 512, 512, (long)NP2 * 512, 0, (long)NP0 * 512, BB, 1, ws.ni2, NP0);

  // x2 = relu(relu(x1) @ h2 + h2_b) -> bf16  (relu on A-load, relu on store)
  mm<0, 0, 1, 2, false, true, false>(stream, ws.x1, in(60), in(61), ws.x2b,
      NP0, 512, 512, (long)NP0 * 512, 0, (long)NP0 * 512, BB, 1);
  // logits = x2b @ h3 + h3_b -> f32 d_out
  mm<2, 0, 1, 0, false, false, false>(stream, ws.x2b, in(62), in(63), out,
      NP0, 50, 512, (long)NP0 * 512, 0, (long)NP0 * 50, BB, 1);

  k_logsoftmax<<<(BB * NP0) / 4, 256, 0, stream>>>(out, BB * NP0, 50);
}